// Round 1
// baseline (2085.996 us; speedup 1.0000x reference)
//
#include <hip/hip_runtime.h>
#include <math.h>

#define BB 64
#define NN 1024
#define DD 1024

// ---------------- Kernel 1: qh = h_t @ W_h.T  [B, D] ----------------
// grid (4, B), 256 threads: each thread computes one qh[b, e].
__global__ __launch_bounds__(256) void qh_kernel(const float* __restrict__ h_t,
                                                 const float* __restrict__ W_h,
                                                 float* __restrict__ qh) {
    __shared__ float hs[DD];
    const int b = blockIdx.y;
    const int e = blockIdx.x * 256 + threadIdx.x;
    for (int i = threadIdx.x; i < DD; i += 256) hs[i] = h_t[b * DD + i];
    __syncthreads();
    const float4* wrow = (const float4*)(W_h + (size_t)e * DD);
    float acc = 0.f;
#pragma unroll 4
    for (int k4 = 0; k4 < DD / 4; ++k4) {
        float4 w = wrow[k4];
        acc = fmaf(w.x, hs[4 * k4 + 0], acc);
        acc = fmaf(w.y, hs[4 * k4 + 1], acc);
        acc = fmaf(w.z, hs[4 * k4 + 2], acc);
        acc = fmaf(w.w, hs[4 * k4 + 3], acc);
    }
    qh[b * DD + e] = acc;
}

// ---------------- Kernel 2: fused scores ----------------
// scores[b,n] = sum_e v[e] * tanh(qh[b,e] + sum_k keys[b,n,k]*W_k[e,k])
// Block: 128 rows (n) x full e-sweep in 128-col passes. 8x8 micro-tile, BK=16.
#define TBM 128
#define TBN 128
#define TBK 16

__device__ __forceinline__ float fast_tanh(float x) {
    // 1 - 2/(e^{2x}+1); saturates correctly for |x| large (inf arithmetic).
    return 1.f - 2.f / (__expf(2.f * x) + 1.f);
}

__global__ __launch_bounds__(256) void scores_kernel(const float* __restrict__ keys,
                                                     const float* __restrict__ W_k,
                                                     const float* __restrict__ v,
                                                     const float* __restrict__ qh,
                                                     float* __restrict__ scores) {
    __shared__ float As[TBK][TBM];   // keys tile, k-major
    __shared__ float Bs[TBK][TBN];   // W_k tile, k-major
    __shared__ float vs[TBN];
    __shared__ float qs[TBN];
    __shared__ float red[TBM][17];

    const int tid = threadIdx.x;
    const int b = blockIdx.y;
    const int n0 = blockIdx.x * TBM;
    const int ti = tid >> 4;  // 0..15 -> rows ti*8..ti*8+7
    const int tj = tid & 15;  // 0..15 -> cols tj*8..tj*8+7
    const float* keysb = keys + ((size_t)b * NN + n0) * DD;

    float sp[8];
#pragma unroll
    for (int i = 0; i < 8; ++i) sp[i] = 0.f;

    for (int et = 0; et < DD / TBN; ++et) {  // 8 passes over e
        const int e0 = et * TBN;
        __syncthreads();  // protect vs/qs/As/Bs from prior-pass readers
        if (tid < TBN) {
            vs[tid] = v[e0 + tid];
            qs[tid] = qh[b * DD + e0 + tid];
        }
        float acc[8][8];
#pragma unroll
        for (int i = 0; i < 8; ++i)
#pragma unroll
            for (int j = 0; j < 8; ++j) acc[i][j] = 0.f;

        for (int kt = 0; kt < DD / TBK; ++kt) {  // 64 k-tiles
            const int k0 = kt * TBK;
            const int row = tid >> 2;  // 0..63
            const int q = tid & 3;
#pragma unroll
            for (int r = 0; r < 2; ++r) {
                float4 a4 = *(const float4*)(keysb + (size_t)(row + 64 * r) * DD + k0 + 4 * q);
                As[4 * q + 0][row + 64 * r] = a4.x;
                As[4 * q + 1][row + 64 * r] = a4.y;
                As[4 * q + 2][row + 64 * r] = a4.z;
                As[4 * q + 3][row + 64 * r] = a4.w;
            }
#pragma unroll
            for (int r = 0; r < 2; ++r) {
                float4 b4 = *(const float4*)(W_k + (size_t)(e0 + row + 64 * r) * DD + k0 + 4 * q);
                Bs[4 * q + 0][row + 64 * r] = b4.x;
                Bs[4 * q + 1][row + 64 * r] = b4.y;
                Bs[4 * q + 2][row + 64 * r] = b4.z;
                Bs[4 * q + 3][row + 64 * r] = b4.w;
            }
            __syncthreads();
#pragma unroll
            for (int k = 0; k < TBK; ++k) {
                float4 a0 = *(const float4*)&As[k][ti * 8];
                float4 a1 = *(const float4*)&As[k][ti * 8 + 4];
                float4 b0 = *(const float4*)&Bs[k][tj * 8];
                float4 b1 = *(const float4*)&Bs[k][tj * 8 + 4];
                float av[8] = {a0.x, a0.y, a0.z, a0.w, a1.x, a1.y, a1.z, a1.w};
                float bv[8] = {b0.x, b0.y, b0.z, b0.w, b1.x, b1.y, b1.z, b1.w};
#pragma unroll
                for (int i = 0; i < 8; ++i)
#pragma unroll
                    for (int j = 0; j < 8; ++j) acc[i][j] = fmaf(av[i], bv[j], acc[i][j]);
            }
            __syncthreads();
        }
        // epilogue: fold this e-pass into the score partials
#pragma unroll
        for (int j = 0; j < 8; ++j) {
            const int e = tj * 8 + j;
            const float w = vs[e];
            const float qv = qs[e];
#pragma unroll
            for (int i = 0; i < 8; ++i) sp[i] += w * fast_tanh(qv + acc[i][j]);
        }
    }
    // cross-thread reduce over tj (16 partials per row)
#pragma unroll
    for (int i = 0; i < 8; ++i) red[ti * 8 + i][tj] = sp[i];
    __syncthreads();
    if (tid < TBM) {
        float s = 0.f;
#pragma unroll
        for (int j = 0; j < 16; ++j) s += red[tid][j];
        scores[b * NN + n0 + tid] = s;
    }
}

// ---------------- Kernel 3: softmax over N per b; also zero context ----------------
__global__ __launch_bounds__(256) void softmax_kernel(const float* __restrict__ scores,
                                                      float* __restrict__ alpha,
                                                      float* __restrict__ context) {
    const int b = blockIdx.x;
    const int t = threadIdx.x;
    // zero the context region for kernel 4's atomics
#pragma unroll
    for (int j = 0; j < 4; ++j) context[b * DD + t + 256 * j] = 0.f;

    float x[4];
    float m = -1e30f;
#pragma unroll
    for (int j = 0; j < 4; ++j) {
        x[j] = scores[b * NN + t + 256 * j];
        m = fmaxf(m, x[j]);
    }
#pragma unroll
    for (int mask = 32; mask >= 1; mask >>= 1) m = fmaxf(m, __shfl_xor(m, mask));
    __shared__ float wred[4];
    __shared__ float wsum[4];
    const int wv = t >> 6;
    if ((t & 63) == 0) wred[wv] = m;
    __syncthreads();
    m = fmaxf(fmaxf(wred[0], wred[1]), fmaxf(wred[2], wred[3]));
    float s = 0.f;
#pragma unroll
    for (int j = 0; j < 4; ++j) {
        x[j] = expf(x[j] - m);
        s += x[j];
    }
#pragma unroll
    for (int mask = 32; mask >= 1; mask >>= 1) s += __shfl_xor(s, mask);
    if ((t & 63) == 0) wsum[wv] = s;
    __syncthreads();
    s = wsum[0] + wsum[1] + wsum[2] + wsum[3];
    const float inv = 1.f / s;
#pragma unroll
    for (int j = 0; j < 4; ++j) alpha[b * NN + t + 256 * j] = x[j] * inv;
}

// ---------------- Kernel 4: context[b,d] = sum_n alpha[b,n]*keys[b,n,d] ----------------
// grid (8, B): each block handles a 128-row n-chunk, atomically accumulates.
__global__ __launch_bounds__(256) void context_kernel(const float* __restrict__ keys,
                                                      const float* __restrict__ alpha,
                                                      float* __restrict__ context) {
    const int b = blockIdx.y;
    const int nc = blockIdx.x;  // 0..7, 128 rows each
    const int t = threadIdx.x;
    __shared__ float al[128];
    if (t < 128) al[t] = alpha[b * NN + nc * 128 + t];
    __syncthreads();
    const float4* kp = (const float4*)(keys + ((size_t)b * NN + nc * 128) * DD);
    float4 acc = {0.f, 0.f, 0.f, 0.f};
#pragma unroll 4
    for (int n = 0; n < 128; ++n) {
        const float a = al[n];
        float4 kv = kp[(size_t)n * (DD / 4) + t];
        acc.x = fmaf(a, kv.x, acc.x);
        acc.y = fmaf(a, kv.y, acc.y);
        acc.z = fmaf(a, kv.z, acc.z);
        acc.w = fmaf(a, kv.w, acc.w);
    }
    float* cp = context + b * DD + 4 * t;
    atomicAdd(cp + 0, acc.x);
    atomicAdd(cp + 1, acc.y);
    atomicAdd(cp + 2, acc.z);
    atomicAdd(cp + 3, acc.w);
}

extern "C" void kernel_launch(void* const* d_in, const int* in_sizes, int n_in,
                              void* d_out, int out_size, void* d_ws, size_t ws_size,
                              hipStream_t stream) {
    const float* h_t = (const float*)d_in[0];
    const float* keys = (const float*)d_in[1];
    const float* W_h = (const float*)d_in[2];
    const float* W_k = (const float*)d_in[3];
    const float* v = (const float*)d_in[4];

    float* context = (float*)d_out;            // [B, D] = 65536 floats
    float* alpha = (float*)d_out + BB * DD;    // [B, N] = 65536 floats
    float* qh = (float*)d_ws;                  // [B, D]
    float* scores = (float*)d_ws + BB * DD;    // [B, N]

    qh_kernel<<<dim3(4, BB), 256, 0, stream>>>(h_t, W_h, qh);
    scores_kernel<<<dim3(NN / TBM, BB), 256, 0, stream>>>(keys, W_k, v, qh, scores);
    softmax_kernel<<<BB, 256, 0, stream>>>(scores, alpha, context);
    context_kernel<<<dim3(8, BB), 256, 0, stream>>>(keys, alpha, context);
}

// Round 2
// 754.732 us; speedup vs baseline: 2.7639x; 2.7639x over previous
//
#include <hip/hip_runtime.h>
#include <math.h>

#define BB 64
#define NN 1024
#define DD 1024

typedef __bf16 bf16x8 __attribute__((ext_vector_type(8)));
typedef float f32x4 __attribute__((ext_vector_type(4)));
typedef unsigned short u16x8 __attribute__((ext_vector_type(8)));

__device__ __forceinline__ float fast_tanh(float x) {
    // 1 - 2/(e^{2x}+1); saturates correctly for |x| large (inf arithmetic).
    return 1.f - 2.f / (__expf(2.f * x) + 1.f);
}

// ---------------- Kernel 1: qh = h_t @ W_h.T  [B, D]; also zero scores ----------------
// grid (4, B), 256 threads: each thread computes one qh[b, e] and zeros one score.
__global__ __launch_bounds__(256) void qh_kernel(const float* __restrict__ h_t,
                                                 const float* __restrict__ W_h,
                                                 float* __restrict__ qh,
                                                 float* __restrict__ scores) {
    __shared__ float hs[DD];
    const int b = blockIdx.y;
    const int e = blockIdx.x * 256 + threadIdx.x;
    // zero scores for scores_kernel's atomics (grid covers exactly B*N elems)
    scores[(blockIdx.y * 4 + blockIdx.x) * 256 + threadIdx.x] = 0.f;
    for (int i = threadIdx.x; i < DD; i += 256) hs[i] = h_t[b * DD + i];
    __syncthreads();
    const float4* wrow = (const float4*)(W_h + (size_t)e * DD);
    float acc = 0.f;
#pragma unroll 4
    for (int k4 = 0; k4 < DD / 4; ++k4) {
        float4 w = wrow[k4];
        acc = fmaf(w.x, hs[4 * k4 + 0], acc);
        acc = fmaf(w.y, hs[4 * k4 + 1], acc);
        acc = fmaf(w.z, hs[4 * k4 + 2], acc);
        acc = fmaf(w.w, hs[4 * k4 + 3], acc);
    }
    qh[b * DD + e] = acc;
}

// ---------------- Kernel 2: fused scores via split-bf16 MFMA ----------------
// scores[b,n] += sum_{e in tile} v[e] * tanh(qh[b,e] + sum_k keys[b,n,k]*W_k[e,k])
// Block = 128 n-rows x 128 e-cols. A = keys (fp32->bf16 hi/lo), B = W_k rows.
// acc via 3 MFMAs: hi*hi + hi*lo + lo*hi  (~fp32 accuracy).
#define SPAD 40  // ushort stride per LDS row (32 + 8 pad -> 80 B, breaks b128 conflicts)

__device__ __forceinline__ void split16(const float4* __restrict__ src,
                                        unsigned short* hi, unsigned short* lo) {
    float x[16];
    float4 v0 = src[0], v1 = src[1], v2 = src[2], v3 = src[3];
    x[0] = v0.x; x[1] = v0.y; x[2] = v0.z; x[3] = v0.w;
    x[4] = v1.x; x[5] = v1.y; x[6] = v1.z; x[7] = v1.w;
    x[8] = v2.x; x[9] = v2.y; x[10] = v2.z; x[11] = v2.w;
    x[12] = v3.x; x[13] = v3.y; x[14] = v3.z; x[15] = v3.w;
#pragma unroll
    for (int i = 0; i < 16; ++i) {
        unsigned int u = __float_as_uint(x[i]);
        hi[i] = (unsigned short)(u >> 16);                   // truncated bf16 (exact residual)
        float hif = __uint_as_float(u & 0xFFFF0000u);
        float lof = x[i] - hif;                              // exact in fp32
        lo[i] = (unsigned short)(__float_as_uint(lof) >> 16);
    }
}

__global__ __launch_bounds__(256, 2) void scores_kernel(const float* __restrict__ keys,
                                                        const float* __restrict__ W_k,
                                                        const float* __restrict__ v,
                                                        const float* __restrict__ qh,
                                                        float* __restrict__ scores) {
    __shared__ unsigned short Ah[128 * SPAD];
    __shared__ unsigned short Al[128 * SPAD];
    __shared__ unsigned short Bh[128 * SPAD];
    __shared__ unsigned short Bl[128 * SPAD];
    __shared__ float vs[128];
    __shared__ float qs[128];
    __shared__ float red[128][2];

    const int tid = threadIdx.x;
    const int cp = blockIdx.x;   // e-col pass 0..7 (fastest-varying: keys L2/L3 reuse)
    const int rt = blockIdx.y;   // row tile 0..511
    const int b = rt >> 3;
    const int n0 = (rt & 7) * 128;
    const int e0 = cp * 128;

    if (tid < 128) {
        vs[tid] = v[e0 + tid];
        qs[tid] = qh[b * DD + e0 + tid];
    }

    const float* Ag = keys + ((size_t)b * NN + n0) * DD;  // [128][1024]
    const float* Bg = W_k + (size_t)e0 * DD;              // [128][1024]

    const int w = tid >> 6;
    const int lane = tid & 63;
    const int wm = w & 1;    // wave n-half
    const int we = w >> 1;   // wave e-half
    const int lcol = lane & 15;
    const int quad = lane >> 4;

    f32x4 acc[4][4];
#pragma unroll
    for (int mi = 0; mi < 4; ++mi)
#pragma unroll
        for (int ni = 0; ni < 4; ++ni) acc[mi][ni] = (f32x4){0.f, 0.f, 0.f, 0.f};

    const int srow = tid >> 1;  // staging row 0..127
    const int sseg = tid & 1;   // 16-float segment

    // prefetch k-tile 0
    float4 pa[4], pb[4];
    {
        const float4* as = (const float4*)(Ag + (size_t)srow * DD + sseg * 16);
        const float4* bs = (const float4*)(Bg + (size_t)srow * DD + sseg * 16);
#pragma unroll
        for (int i = 0; i < 4; ++i) { pa[i] = as[i]; pb[i] = bs[i]; }
    }

    for (int kt = 0; kt < DD / 32; ++kt) {
        __syncthreads();  // prior iteration's MFMA LDS reads done
        {
            unsigned short hi[16], lo[16];
            split16(pa, hi, lo);
            u16x8* dh = (u16x8*)&Ah[srow * SPAD + sseg * 16];
            u16x8* dl = (u16x8*)&Al[srow * SPAD + sseg * 16];
            dh[0] = *(u16x8*)&hi[0]; dh[1] = *(u16x8*)&hi[8];
            dl[0] = *(u16x8*)&lo[0]; dl[1] = *(u16x8*)&lo[8];
            split16(pb, hi, lo);
            u16x8* eh = (u16x8*)&Bh[srow * SPAD + sseg * 16];
            u16x8* el = (u16x8*)&Bl[srow * SPAD + sseg * 16];
            eh[0] = *(u16x8*)&hi[0]; eh[1] = *(u16x8*)&hi[8];
            el[0] = *(u16x8*)&lo[0]; el[1] = *(u16x8*)&lo[8];
        }
        // prefetch next k-tile while MFMAs run
        if (kt + 1 < DD / 32) {
            const int k0 = (kt + 1) * 32;
            const float4* as = (const float4*)(Ag + (size_t)srow * DD + k0 + sseg * 16);
            const float4* bs = (const float4*)(Bg + (size_t)srow * DD + k0 + sseg * 16);
#pragma unroll
            for (int i = 0; i < 4; ++i) { pa[i] = as[i]; pb[i] = bs[i]; }
        }
        __syncthreads();  // LDS tiles ready

        bf16x8 ah[4], al[4], bh[4], bl[4];
#pragma unroll
        for (int mi = 0; mi < 4; ++mi) {
            const int r = wm * 64 + mi * 16 + lcol;
            ah[mi] = *(const bf16x8*)&Ah[r * SPAD + quad * 8];
            al[mi] = *(const bf16x8*)&Al[r * SPAD + quad * 8];
        }
#pragma unroll
        for (int ni = 0; ni < 4; ++ni) {
            const int r = we * 64 + ni * 16 + lcol;
            bh[ni] = *(const bf16x8*)&Bh[r * SPAD + quad * 8];
            bl[ni] = *(const bf16x8*)&Bl[r * SPAD + quad * 8];
        }
#pragma unroll
        for (int mi = 0; mi < 4; ++mi)
#pragma unroll
            for (int ni = 0; ni < 4; ++ni) {
                acc[mi][ni] = __builtin_amdgcn_mfma_f32_16x16x32_bf16(ah[mi], bh[ni], acc[mi][ni], 0, 0, 0);
                acc[mi][ni] = __builtin_amdgcn_mfma_f32_16x16x32_bf16(ah[mi], bl[ni], acc[mi][ni], 0, 0, 0);
                acc[mi][ni] = __builtin_amdgcn_mfma_f32_16x16x32_bf16(al[mi], bh[ni], acc[mi][ni], 0, 0, 0);
            }
    }

    // epilogue: score partial = sum_e v[e]*tanh(qh[e] + acc)
    // C/D layout: col = lane&15 (e), row = quad*4 + reg (n)
    float part[4][4];  // [mi][reg]
#pragma unroll
    for (int mi = 0; mi < 4; ++mi)
#pragma unroll
        for (int r = 0; r < 4; ++r) part[mi][r] = 0.f;
#pragma unroll
    for (int mi = 0; mi < 4; ++mi)
#pragma unroll
        for (int ni = 0; ni < 4; ++ni) {
            const int e = we * 64 + ni * 16 + lcol;
            const float vv = vs[e];
            const float qv = qs[e];
#pragma unroll
            for (int r = 0; r < 4; ++r)
                part[mi][r] += vv * fast_tanh(qv + acc[mi][ni][r]);
        }
#pragma unroll
    for (int mi = 0; mi < 4; ++mi)
#pragma unroll
        for (int r = 0; r < 4; ++r) {
            float p = part[mi][r];
            p += __shfl_xor(p, 1);
            p += __shfl_xor(p, 2);
            p += __shfl_xor(p, 4);
            p += __shfl_xor(p, 8);
            if (lcol == 0) red[wm * 64 + mi * 16 + quad * 4 + r][we] = p;
        }
    __syncthreads();
    if (tid < 128) atomicAdd(&scores[b * NN + n0 + tid], red[tid][0] + red[tid][1]);
}

// ---------------- Kernel 3: softmax over N per b; also zero context ----------------
__global__ __launch_bounds__(256) void softmax_kernel(const float* __restrict__ scores,
                                                      float* __restrict__ alpha,
                                                      float* __restrict__ context) {
    const int b = blockIdx.x;
    const int t = threadIdx.x;
#pragma unroll
    for (int j = 0; j < 4; ++j) context[b * DD + t + 256 * j] = 0.f;

    float x[4];
    float m = -1e30f;
#pragma unroll
    for (int j = 0; j < 4; ++j) {
        x[j] = scores[b * NN + t + 256 * j];
        m = fmaxf(m, x[j]);
    }
#pragma unroll
    for (int mask = 32; mask >= 1; mask >>= 1) m = fmaxf(m, __shfl_xor(m, mask));
    __shared__ float wred[4];
    __shared__ float wsum[4];
    const int wv = t >> 6;
    if ((t & 63) == 0) wred[wv] = m;
    __syncthreads();
    m = fmaxf(fmaxf(wred[0], wred[1]), fmaxf(wred[2], wred[3]));
    float s = 0.f;
#pragma unroll
    for (int j = 0; j < 4; ++j) {
        x[j] = expf(x[j] - m);
        s += x[j];
    }
#pragma unroll
    for (int mask = 32; mask >= 1; mask >>= 1) s += __shfl_xor(s, mask);
    if ((t & 63) == 0) wsum[wv] = s;
    __syncthreads();
    s = wsum[0] + wsum[1] + wsum[2] + wsum[3];
    const float inv = 1.f / s;
#pragma unroll
    for (int j = 0; j < 4; ++j) alpha[b * NN + t + 256 * j] = x[j] * inv;
}

// ---------------- Kernel 4: context[b,d] = sum_n alpha[b,n]*keys[b,n,d] ----------------
__global__ __launch_bounds__(256) void context_kernel(const float* __restrict__ keys,
                                                      const float* __restrict__ alpha,
                                                      float* __restrict__ context) {
    const int b = blockIdx.y;
    const int nc = blockIdx.x;  // 0..7, 128 rows each
    const int t = threadIdx.x;
    __shared__ float al[128];
    if (t < 128) al[t] = alpha[b * NN + nc * 128 + t];
    __syncthreads();
    const float4* kp = (const float4*)(keys + ((size_t)b * NN + nc * 128) * DD);
    float4 acc = {0.f, 0.f, 0.f, 0.f};
#pragma unroll 4
    for (int n = 0; n < 128; ++n) {
        const float a = al[n];
        float4 kv = kp[(size_t)n * (DD / 4) + t];
        acc.x = fmaf(a, kv.x, acc.x);
        acc.y = fmaf(a, kv.y, acc.y);
        acc.z = fmaf(a, kv.z, acc.z);
        acc.w = fmaf(a, kv.w, acc.w);
    }
    float* cp = context + b * DD + 4 * t;
    atomicAdd(cp + 0, acc.x);
    atomicAdd(cp + 1, acc.y);
    atomicAdd(cp + 2, acc.z);
    atomicAdd(cp + 3, acc.w);
}

extern "C" void kernel_launch(void* const* d_in, const int* in_sizes, int n_in,
                              void* d_out, int out_size, void* d_ws, size_t ws_size,
                              hipStream_t stream) {
    const float* h_t = (const float*)d_in[0];
    const float* keys = (const float*)d_in[1];
    const float* W_h = (const float*)d_in[2];
    const float* W_k = (const float*)d_in[3];
    const float* v = (const float*)d_in[4];

    float* context = (float*)d_out;          // [B, D]
    float* alpha = (float*)d_out + BB * DD;  // [B, N]
    float* qh = (float*)d_ws;                // [B, D]
    float* scores = (float*)d_ws + BB * DD;  // [B, N]

    qh_kernel<<<dim3(4, BB), 256, 0, stream>>>(h_t, W_h, qh, scores);
    scores_kernel<<<dim3(8, 512), 256, 0, stream>>>(keys, W_k, v, qh, scores);
    softmax_kernel<<<BB, 256, 0, stream>>>(scores, alpha, context);
    context_kernel<<<dim3(8, BB), 256, 0, stream>>>(keys, alpha, context);
}

// Round 3
// 677.105 us; speedup vs baseline: 3.0808x; 1.1146x over previous
//
#include <hip/hip_runtime.h>
#include <math.h>

#define BB 64
#define NN 1024
#define DD 1024

typedef __bf16 bf16x8 __attribute__((ext_vector_type(8)));
typedef _Float16 f16x8 __attribute__((ext_vector_type(8)));
typedef _Float16 f16x4 __attribute__((ext_vector_type(4)));
typedef float f32x4 __attribute__((ext_vector_type(4)));
typedef unsigned short u16x8 __attribute__((ext_vector_type(8)));

#define GLOAD_LDS16(g, l)                                                  \
    __builtin_amdgcn_global_load_lds(                                      \
        (const __attribute__((address_space(1))) unsigned int*)(g),        \
        (__attribute__((address_space(3))) unsigned int*)(l), 16, 0, 0)

__device__ __forceinline__ float fast_tanh(float x) {
    return 1.f - 2.f / (__expf(2.f * x) + 1.f);
}

// =========================== FAST PATH ===========================
// ws layout (floats unless noted):
//   qh      [BB*DD]                      @ 0
//   scores  [BB*NN]                      @ 65536
//   wkT     fp16 [8 et][32 kt][128*32]   @ byte 524288   (2 MB)
//   keysT   fp16 [64 b][8 nt][32 kt][128*32] @ byte 2621440 (128 MB)

// ---- pre-pass: keys fp32 -> fp16 in (b, ntile, ktile, row-major 128x32) chunks ----
__global__ __launch_bounds__(256) void cvt_keys(const float* __restrict__ keys,
                                                _Float16* __restrict__ keysT) {
    const int b = blockIdx.y;   // 64
    const int nt = blockIdx.x;  // 8
    const int t = threadIdx.x;
    const float4* src = (const float4*)(keys + ((size_t)b * NN + nt * 128) * DD);
    _Float16* dst = keysT + (((size_t)b * 8 + nt) * 32) * 4096;
    const int kt = t >> 3;
    const int kc = (t & 7) * 4;
    _Float16* dcol = dst + (size_t)kt * 4096 + kc;
#pragma unroll 4
    for (int n = 0; n < 128; ++n) {
        float4 v4 = src[n * 256 + t];
        f16x4 h = {(_Float16)v4.x, (_Float16)v4.y, (_Float16)v4.z, (_Float16)v4.w};
        *(f16x4*)(dcol + n * 32) = h;
    }
}

// ---- pre-pass: W_k fp32 -> fp16 in (etile, ktile, 128x32) chunks ----
__global__ __launch_bounds__(256) void cvt_wk(const float* __restrict__ W_k,
                                              _Float16* __restrict__ wkT) {
    const int et = blockIdx.x;  // 8
    const int t = threadIdx.x;
    const float4* src = (const float4*)(W_k + (size_t)et * 128 * DD);
    _Float16* dst = wkT + ((size_t)et * 32) * 4096;
    const int kt = t >> 3;
    const int kc = (t & 7) * 4;
    _Float16* dcol = dst + (size_t)kt * 4096 + kc;
#pragma unroll 4
    for (int n = 0; n < 128; ++n) {
        float4 v4 = src[n * 256 + t];
        f16x4 h = {(_Float16)v4.x, (_Float16)v4.y, (_Float16)v4.z, (_Float16)v4.w};
        *(f16x4*)(dcol + n * 32) = h;
    }
}

// ---- qh = h_t @ W_h.T, W_h read 16x (not 64x); also zero scores ----
// grid (4, 16): 256 e-cols x 4 b-rows per block.
__global__ __launch_bounds__(256) void qh_fast(const float* __restrict__ h_t,
                                               const float* __restrict__ W_h,
                                               float* __restrict__ qh,
                                               float* __restrict__ scores) {
    __shared__ float hs[4 * 1024];
    const int ec = blockIdx.x;  // 0..3
    const int bg = blockIdx.y;  // 0..15
    const int t = threadIdx.x;
    const int flat = bg * 4 + ec;
#pragma unroll
    for (int j = 0; j < 4; ++j) scores[flat * 1024 + j * 256 + t] = 0.f;
    const float4* hsrc = (const float4*)(h_t + (size_t)bg * 4 * DD);
    float4* hdst = (float4*)hs;
    for (int i = t; i < 1024; i += 256) hdst[i] = hsrc[i];
    __syncthreads();
    const int e = ec * 256 + t;
    const float4* wrow = (const float4*)(W_h + (size_t)e * DD);
    float a0 = 0.f, a1 = 0.f, a2 = 0.f, a3 = 0.f;
#pragma unroll 2
    for (int k4 = 0; k4 < 256; ++k4) {
        float4 wv = wrow[k4];
        const float* h0 = &hs[4 * k4];
        a0 = fmaf(wv.x, h0[0], a0); a0 = fmaf(wv.y, h0[1], a0);
        a0 = fmaf(wv.z, h0[2], a0); a0 = fmaf(wv.w, h0[3], a0);
        const float* h1 = &hs[1024 + 4 * k4];
        a1 = fmaf(wv.x, h1[0], a1); a1 = fmaf(wv.y, h1[1], a1);
        a1 = fmaf(wv.z, h1[2], a1); a1 = fmaf(wv.w, h1[3], a1);
        const float* h2 = &hs[2048 + 4 * k4];
        a2 = fmaf(wv.x, h2[0], a2); a2 = fmaf(wv.y, h2[1], a2);
        a2 = fmaf(wv.z, h2[2], a2); a2 = fmaf(wv.w, h2[3], a2);
        const float* h3 = &hs[3072 + 4 * k4];
        a3 = fmaf(wv.x, h3[0], a3); a3 = fmaf(wv.y, h3[1], a3);
        a3 = fmaf(wv.z, h3[2], a3); a3 = fmaf(wv.w, h3[3], a3);
    }
    const int b0 = bg * 4;
    qh[(b0 + 0) * DD + e] = a0;
    qh[(b0 + 1) * DD + e] = a1;
    qh[(b0 + 2) * DD + e] = a2;
    qh[(b0 + 3) * DD + e] = a3;
}

// ---- scores: m97-style fp16 MFMA GEMM + fused tanh/v-dot epilogue ----
// Block = 128 n-rows x 128 e-cols, BK=32, global_load_lds staging.
__global__ __launch_bounds__(256) void scores_mfma(const _Float16* __restrict__ keysT,
                                                   const _Float16* __restrict__ wkT,
                                                   const float* __restrict__ v,
                                                   const float* __restrict__ qh,
                                                   float* __restrict__ scores) {
    __shared__ _Float16 As[128 * 32];
    __shared__ _Float16 Bs[128 * 32];
    __shared__ float vs[128];
    __shared__ float qs[128];
    __shared__ float red[128][2];

    const int tid = threadIdx.x;
    const int cp = blockIdx.x;  // e-tile 0..7 (fastest: keys tile shared by 8 blocks)
    const int rt = blockIdx.y;  // 0..511
    const int b = rt >> 3;
    const int nt = rt & 7;
    const int e0 = cp * 128;

    if (tid < 128) {
        vs[tid] = v[e0 + tid];
        qs[tid] = qh[b * DD + e0 + tid];
    }

    const char* Abase = (const char*)(keysT + (((size_t)b * 8 + nt) * 32) * 4096);
    const char* Bbase = (const char*)(wkT + ((size_t)cp * 32) * 4096);

    const int w = tid >> 6;
    const int lane = tid & 63;
    const int wm = w & 1;
    const int we = w >> 1;
    const int lcol = lane & 15;
    const int quad = lane >> 4;
    const int soff = w * 2048 + lane * 16;  // this lane's staging byte offset

    f32x4 acc[4][4];
#pragma unroll
    for (int mi = 0; mi < 4; ++mi)
#pragma unroll
        for (int ni = 0; ni < 4; ++ni) acc[mi][ni] = (f32x4){0.f, 0.f, 0.f, 0.f};

    for (int kt = 0; kt < 32; ++kt) {
        __syncthreads();  // prior iteration's LDS reads done
        const char* ag = Abase + (size_t)kt * 8192 + soff;
        const char* bg = Bbase + (size_t)kt * 8192 + soff;
        char* al_ = (char*)As + soff;
        char* bl_ = (char*)Bs + soff;
        GLOAD_LDS16(ag, al_);
        GLOAD_LDS16(ag + 1024, al_ + 1024);
        GLOAD_LDS16(bg, bl_);
        GLOAD_LDS16(bg + 1024, bl_ + 1024);
        __syncthreads();  // staging complete (vmcnt(0) drained before barrier)

        f16x8 af[4], bf[4];
#pragma unroll
        for (int mi = 0; mi < 4; ++mi)
            af[mi] = *(const f16x8*)&As[(wm * 64 + mi * 16 + lcol) * 32 + quad * 8];
#pragma unroll
        for (int ni = 0; ni < 4; ++ni)
            bf[ni] = *(const f16x8*)&Bs[(we * 64 + ni * 16 + lcol) * 32 + quad * 8];
#pragma unroll
        for (int mi = 0; mi < 4; ++mi)
#pragma unroll
            for (int ni = 0; ni < 4; ++ni)
                acc[mi][ni] = __builtin_amdgcn_mfma_f32_16x16x32_f16(af[mi], bf[ni], acc[mi][ni], 0, 0, 0);
    }

    // epilogue: partial score = sum_e v[e]*tanh(qh[e]+acc); C/D: col=lane&15(e), row=quad*4+reg(n)
    float part[4][4];
#pragma unroll
    for (int mi = 0; mi < 4; ++mi)
#pragma unroll
        for (int r = 0; r < 4; ++r) part[mi][r] = 0.f;
#pragma unroll
    for (int mi = 0; mi < 4; ++mi)
#pragma unroll
        for (int ni = 0; ni < 4; ++ni) {
            const int e = we * 64 + ni * 16 + lcol;
            const float vv = vs[e];
            const float qv = qs[e];
#pragma unroll
            for (int r = 0; r < 4; ++r)
                part[mi][r] += vv * fast_tanh(qv + acc[mi][ni][r]);
        }
#pragma unroll
    for (int mi = 0; mi < 4; ++mi)
#pragma unroll
        for (int r = 0; r < 4; ++r) {
            float p = part[mi][r];
            p += __shfl_xor(p, 1);
            p += __shfl_xor(p, 2);
            p += __shfl_xor(p, 4);
            p += __shfl_xor(p, 8);
            if (lcol == 0) red[wm * 64 + mi * 16 + quad * 4 + r][we] = p;
        }
    __syncthreads();
    if (tid < 128) atomicAdd(&scores[b * NN + nt * 128 + tid], red[tid][0] + red[tid][1]);
}

// ---- softmax (shared by both paths); zeroes context ----
__global__ __launch_bounds__(256) void softmax_kernel(const float* __restrict__ scores,
                                                      float* __restrict__ alpha,
                                                      float* __restrict__ context) {
    const int b = blockIdx.x;
    const int t = threadIdx.x;
#pragma unroll
    for (int j = 0; j < 4; ++j) context[b * DD + t + 256 * j] = 0.f;
    float x[4];
    float m = -1e30f;
#pragma unroll
    for (int j = 0; j < 4; ++j) {
        x[j] = scores[b * NN + t + 256 * j];
        m = fmaxf(m, x[j]);
    }
#pragma unroll
    for (int mask = 32; mask >= 1; mask >>= 1) m = fmaxf(m, __shfl_xor(m, mask));
    __shared__ float wred[4];
    __shared__ float wsum[4];
    const int wv = t >> 6;
    if ((t & 63) == 0) wred[wv] = m;
    __syncthreads();
    m = fmaxf(fmaxf(wred[0], wred[1]), fmaxf(wred[2], wred[3]));
    float s = 0.f;
#pragma unroll
    for (int j = 0; j < 4; ++j) {
        x[j] = expf(x[j] - m);
        s += x[j];
    }
#pragma unroll
    for (int mask = 32; mask >= 1; mask >>= 1) s += __shfl_xor(s, mask);
    if ((t & 63) == 0) wsum[wv] = s;
    __syncthreads();
    s = wsum[0] + wsum[1] + wsum[2] + wsum[3];
    const float inv = 1.f / s;
#pragma unroll
    for (int j = 0; j < 4; ++j) alpha[b * NN + t + 256 * j] = x[j] * inv;
}

// ---- context from fp16 tiled keys ----
__global__ __launch_bounds__(256) void context_f16(const _Float16* __restrict__ keysT,
                                                   const float* __restrict__ alpha,
                                                   float* __restrict__ context) {
    const int b = blockIdx.y;
    const int nc = blockIdx.x;  // 0..7
    const int t = threadIdx.x;
    __shared__ float al[128];
    if (t < 128) al[t] = alpha[b * NN + nc * 128 + t];
    __syncthreads();
    const _Float16* chunk = keysT + (((size_t)b * 8 + nc) * 32) * 4096;
    const int kt = t >> 3;
    const int kc = (t & 7) * 4;
    const _Float16* p = chunk + (size_t)kt * 4096 + kc;
    float4 acc = {0.f, 0.f, 0.f, 0.f};
#pragma unroll 4
    for (int n = 0; n < 128; ++n) {
        const float a = al[n];
        f16x4 kv = *(const f16x4*)(p + n * 32);
        acc.x = fmaf(a, (float)kv[0], acc.x);
        acc.y = fmaf(a, (float)kv[1], acc.y);
        acc.z = fmaf(a, (float)kv[2], acc.z);
        acc.w = fmaf(a, (float)kv[3], acc.w);
    }
    float* cp = context + b * DD + kt * 32 + kc;
    atomicAdd(cp + 0, acc.x);
    atomicAdd(cp + 1, acc.y);
    atomicAdd(cp + 2, acc.z);
    atomicAdd(cp + 3, acc.w);
}

// =========================== FALLBACK PATH (round-2, used if ws too small) ===========================
__global__ __launch_bounds__(256) void qh_fb(const float* __restrict__ h_t,
                                             const float* __restrict__ W_h,
                                             float* __restrict__ qh,
                                             float* __restrict__ scores) {
    __shared__ float hs[DD];
    const int b = blockIdx.y;
    const int e = blockIdx.x * 256 + threadIdx.x;
    scores[(blockIdx.y * 4 + blockIdx.x) * 256 + threadIdx.x] = 0.f;
    for (int i = threadIdx.x; i < DD; i += 256) hs[i] = h_t[b * DD + i];
    __syncthreads();
    const float4* wrow = (const float4*)(W_h + (size_t)e * DD);
    float acc = 0.f;
#pragma unroll 4
    for (int k4 = 0; k4 < DD / 4; ++k4) {
        float4 w = wrow[k4];
        acc = fmaf(w.x, hs[4 * k4 + 0], acc);
        acc = fmaf(w.y, hs[4 * k4 + 1], acc);
        acc = fmaf(w.z, hs[4 * k4 + 2], acc);
        acc = fmaf(w.w, hs[4 * k4 + 3], acc);
    }
    qh[b * DD + e] = acc;
}

#define SPAD 40
__device__ __forceinline__ void split16(const float4* __restrict__ src,
                                        unsigned short* hi, unsigned short* lo) {
    float x[16];
    float4 v0 = src[0], v1 = src[1], v2 = src[2], v3 = src[3];
    x[0] = v0.x; x[1] = v0.y; x[2] = v0.z; x[3] = v0.w;
    x[4] = v1.x; x[5] = v1.y; x[6] = v1.z; x[7] = v1.w;
    x[8] = v2.x; x[9] = v2.y; x[10] = v2.z; x[11] = v2.w;
    x[12] = v3.x; x[13] = v3.y; x[14] = v3.z; x[15] = v3.w;
#pragma unroll
    for (int i = 0; i < 16; ++i) {
        unsigned int u = __float_as_uint(x[i]);
        hi[i] = (unsigned short)(u >> 16);
        float hif = __uint_as_float(u & 0xFFFF0000u);
        float lof = x[i] - hif;
        lo[i] = (unsigned short)(__float_as_uint(lof) >> 16);
    }
}

__global__ __launch_bounds__(256, 2) void scores_fb(const float* __restrict__ keys,
                                                    const float* __restrict__ W_k,
                                                    const float* __restrict__ v,
                                                    const float* __restrict__ qh,
                                                    float* __restrict__ scores) {
    __shared__ unsigned short Ah[128 * SPAD];
    __shared__ unsigned short Al[128 * SPAD];
    __shared__ unsigned short Bh[128 * SPAD];
    __shared__ unsigned short Bl[128 * SPAD];
    __shared__ float vs[128];
    __shared__ float qs[128];
    __shared__ float red[128][2];

    const int tid = threadIdx.x;
    const int cp = blockIdx.x;
    const int rt = blockIdx.y;
    const int b = rt >> 3;
    const int n0 = (rt & 7) * 128;
    const int e0 = cp * 128;
    if (tid < 128) {
        vs[tid] = v[e0 + tid];
        qs[tid] = qh[b * DD + e0 + tid];
    }
    const float* Ag = keys + ((size_t)b * NN + n0) * DD;
    const float* Bg = W_k + (size_t)e0 * DD;
    const int w = tid >> 6;
    const int lane = tid & 63;
    const int wm = w & 1;
    const int we = w >> 1;
    const int lcol = lane & 15;
    const int quad = lane >> 4;
    f32x4 acc[4][4];
#pragma unroll
    for (int mi = 0; mi < 4; ++mi)
#pragma unroll
        for (int ni = 0; ni < 4; ++ni) acc[mi][ni] = (f32x4){0.f, 0.f, 0.f, 0.f};
    const int srow = tid >> 1;
    const int sseg = tid & 1;
    float4 pa[4], pb[4];
    {
        const float4* as = (const float4*)(Ag + (size_t)srow * DD + sseg * 16);
        const float4* bs = (const float4*)(Bg + (size_t)srow * DD + sseg * 16);
#pragma unroll
        for (int i = 0; i < 4; ++i) { pa[i] = as[i]; pb[i] = bs[i]; }
    }
    for (int kt = 0; kt < DD / 32; ++kt) {
        __syncthreads();
        {
            unsigned short hi[16], lo[16];
            split16(pa, hi, lo);
            u16x8* dh = (u16x8*)&Ah[srow * SPAD + sseg * 16];
            u16x8* dl = (u16x8*)&Al[srow * SPAD + sseg * 16];
            dh[0] = *(u16x8*)&hi[0]; dh[1] = *(u16x8*)&hi[8];
            dl[0] = *(u16x8*)&lo[0]; dl[1] = *(u16x8*)&lo[8];
            split16(pb, hi, lo);
            u16x8* eh = (u16x8*)&Bh[srow * SPAD + sseg * 16];
            u16x8* el = (u16x8*)&Bl[srow * SPAD + sseg * 16];
            eh[0] = *(u16x8*)&hi[0]; eh[1] = *(u16x8*)&hi[8];
            el[0] = *(u16x8*)&lo[0]; el[1] = *(u16x8*)&lo[8];
        }
        if (kt + 1 < DD / 32) {
            const int k0 = (kt + 1) * 32;
            const float4* as = (const float4*)(Ag + (size_t)srow * DD + k0 + sseg * 16);
            const float4* bs = (const float4*)(Bg + (size_t)srow * DD + k0 + sseg * 16);
#pragma unroll
            for (int i = 0; i < 4; ++i) { pa[i] = as[i]; pb[i] = bs[i]; }
        }
        __syncthreads();
        bf16x8 ah[4], al2[4], bh[4], bl2[4];
#pragma unroll
        for (int mi = 0; mi < 4; ++mi) {
            const int r = wm * 64 + mi * 16 + lcol;
            ah[mi] = *(const bf16x8*)&Ah[r * SPAD + quad * 8];
            al2[mi] = *(const bf16x8*)&Al[r * SPAD + quad * 8];
        }
#pragma unroll
        for (int ni = 0; ni < 4; ++ni) {
            const int r = we * 64 + ni * 16 + lcol;
            bh[ni] = *(const bf16x8*)&Bh[r * SPAD + quad * 8];
            bl2[ni] = *(const bf16x8*)&Bl[r * SPAD + quad * 8];
        }
#pragma unroll
        for (int mi = 0; mi < 4; ++mi)
#pragma unroll
            for (int ni = 0; ni < 4; ++ni) {
                acc[mi][ni] = __builtin_amdgcn_mfma_f32_16x16x32_bf16(ah[mi], bh[ni], acc[mi][ni], 0, 0, 0);
                acc[mi][ni] = __builtin_amdgcn_mfma_f32_16x16x32_bf16(ah[mi], bl2[ni], acc[mi][ni], 0, 0, 0);
                acc[mi][ni] = __builtin_amdgcn_mfma_f32_16x16x32_bf16(al2[mi], bh[ni], acc[mi][ni], 0, 0, 0);
            }
    }
    float part[4][4];
#pragma unroll
    for (int mi = 0; mi < 4; ++mi)
#pragma unroll
        for (int r = 0; r < 4; ++r) part[mi][r] = 0.f;
#pragma unroll
    for (int mi = 0; mi < 4; ++mi)
#pragma unroll
        for (int ni = 0; ni < 4; ++ni) {
            const int e = we * 64 + ni * 16 + lcol;
            const float vv = vs[e];
            const float qv = qs[e];
#pragma unroll
            for (int r = 0; r < 4; ++r)
                part[mi][r] += vv * fast_tanh(qv + acc[mi][ni][r]);
        }
#pragma unroll
    for (int mi = 0; mi < 4; ++mi)
#pragma unroll
        for (int r = 0; r < 4; ++r) {
            float p = part[mi][r];
            p += __shfl_xor(p, 1);
            p += __shfl_xor(p, 2);
            p += __shfl_xor(p, 4);
            p += __shfl_xor(p, 8);
            if (lcol == 0) red[wm * 64 + mi * 16 + quad * 4 + r][we] = p;
        }
    __syncthreads();
    if (tid < 128) atomicAdd(&scores[b * NN + n0 + tid], red[tid][0] + red[tid][1]);
}

__global__ __launch_bounds__(256) void context_fb(const float* __restrict__ keys,
                                                  const float* __restrict__ alpha,
                                                  float* __restrict__ context) {
    const int b = blockIdx.y;
    const int nc = blockIdx.x;
    const int t = threadIdx.x;
    __shared__ float al[128];
    if (t < 128) al[t] = alpha[b * NN + nc * 128 + t];
    __syncthreads();
    const float4* kp = (const float4*)(keys + ((size_t)b * NN + nc * 128) * DD);
    float4 acc = {0.f, 0.f, 0.f, 0.f};
#pragma unroll 4
    for (int n = 0; n < 128; ++n) {
        const float a = al[n];
        float4 kv = kp[(size_t)n * (DD / 4) + t];
        acc.x = fmaf(a, kv.x, acc.x);
        acc.y = fmaf(a, kv.y, acc.y);
        acc.z = fmaf(a, kv.z, acc.z);
        acc.w = fmaf(a, kv.w, acc.w);
    }
    float* cp = context + b * DD + 4 * t;
    atomicAdd(cp + 0, acc.x);
    atomicAdd(cp + 1, acc.y);
    atomicAdd(cp + 2, acc.z);
    atomicAdd(cp + 3, acc.w);
}

extern "C" void kernel_launch(void* const* d_in, const int* in_sizes, int n_in,
                              void* d_out, int out_size, void* d_ws, size_t ws_size,
                              hipStream_t stream) {
    const float* h_t = (const float*)d_in[0];
    const float* keys = (const float*)d_in[1];
    const float* W_h = (const float*)d_in[2];
    const float* W_k = (const float*)d_in[3];
    const float* v = (const float*)d_in[4];

    float* context = (float*)d_out;          // [B, D]
    float* alpha = (float*)d_out + BB * DD;  // [B, N]
    float* qh = (float*)d_ws;                // [B, D]
    float* scores = (float*)d_ws + BB * DD;  // [B, N]

    const size_t wkT_off = (size_t)2 * BB * DD * sizeof(float);       // 524288 B
    const size_t keysT_off = wkT_off + (size_t)DD * DD * 2;           // +2 MB
    const size_t need = keysT_off + (size_t)BB * NN * DD * 2;         // +128 MB

    if (ws_size >= need) {
        _Float16* wkT = (_Float16*)((char*)d_ws + wkT_off);
        _Float16* keysT = (_Float16*)((char*)d_ws + keysT_off);
        cvt_keys<<<dim3(8, BB), 256, 0, stream>>>(keys, keysT);
        cvt_wk<<<dim3(8), 256, 0, stream>>>(W_k, wkT);
        qh_fast<<<dim3(4, 16), 256, 0, stream>>>(h_t, W_h, qh, scores);
        scores_mfma<<<dim3(8, 512), 256, 0, stream>>>(keysT, wkT, v, qh, scores);
        softmax_kernel<<<BB, 256, 0, stream>>>(scores, alpha, context);
        context_f16<<<dim3(8, BB), 256, 0, stream>>>(keysT, alpha, context);
    } else {
        qh_fb<<<dim3(4, BB), 256, 0, stream>>>(h_t, W_h, qh, scores);
        scores_fb<<<dim3(8, 512), 256, 0, stream>>>(keys, W_k, v, qh, scores);
        softmax_kernel<<<BB, 256, 0, stream>>>(scores, alpha, context);
        context_fb<<<dim3(8, BB), 256, 0, stream>>>(keys, alpha, context);
    }
}

// Round 4
// 646.649 us; speedup vs baseline: 3.2259x; 1.0471x over previous
//
#include <hip/hip_runtime.h>
#include <math.h>

#define BB 64
#define NN 1024
#define DD 1024

typedef __bf16 bf16x8 __attribute__((ext_vector_type(8)));
typedef _Float16 f16x8 __attribute__((ext_vector_type(8)));
typedef _Float16 f16x4 __attribute__((ext_vector_type(4)));
typedef float f32x4 __attribute__((ext_vector_type(4)));
typedef unsigned short u16x8 __attribute__((ext_vector_type(8)));

#define GLOAD_LDS16(g, l)                                                  \
    __builtin_amdgcn_global_load_lds(                                      \
        (const __attribute__((address_space(1))) unsigned int*)(g),        \
        (__attribute__((address_space(3))) unsigned int*)(l), 16, 0, 0)

__device__ __forceinline__ float fast_tanh(float x) {
    return 1.f - 2.f / (__expf(2.f * x) + 1.f);
}

// =========================== FAST PATH ===========================
// ws layout:
//   qh      fp32 [BB*DD]                     @ 0
//   scores  fp32 [BB*NN]                     @ 65536 floats
//   wkT     fp16 [8 et][32 kt][128*32]       @ byte 524288   (2 MB)
//   keysT   fp16 [64 b][8 nt][32 kt][128*32] @ byte 2621440  (128 MB)

// ---- pre-pass: keys (and W_k as batch row 64) fp32 -> fp16 tiled chunks ----
// Writes: each wave stores 1 KB contiguous. Reads: 128 B contiguous per row segment.
__global__ __launch_bounds__(256) void cvt_all(const float* __restrict__ keys,
                                               const float* __restrict__ W_k,
                                               _Float16* __restrict__ keysT,
                                               _Float16* __restrict__ wkT) {
    const int nt = blockIdx.x;  // 8
    const int bb = blockIdx.y;  // 0..64 (64 = W_k)
    const int t = threadIdx.x;
    const float* src = (bb == 64) ? (W_k + (size_t)nt * 128 * DD)
                                  : (keys + ((size_t)bb * NN + nt * 128) * DD);
    _Float16* dst = (bb == 64) ? (wkT + (size_t)nt * 32 * 4096)
                               : (keysT + (((size_t)bb * 8 + nt) * 32) * 4096);
    for (int kt = 0; kt < 32; ++kt) {
#pragma unroll
        for (int r = 0; r < 2; ++r) {
            const int p = r * 2048 + t * 8;   // elem offset in 128x32 chunk
            const int n = p >> 5;
            const int k = p & 31;
            const float4* s4 = (const float4*)(src + (size_t)n * DD + kt * 32 + k);
            float4 a = s4[0], b4 = s4[1];
            f16x8 h = {(_Float16)a.x,  (_Float16)a.y,  (_Float16)a.z,  (_Float16)a.w,
                       (_Float16)b4.x, (_Float16)b4.y, (_Float16)b4.z, (_Float16)b4.w};
            *(f16x8*)(dst + (size_t)kt * 4096 + p) = h;
        }
    }
}

// ---- qh = h_t @ W_h.T: grid (8 et, 8 bg); 2 threads/e split k; also zero scores ----
__global__ __launch_bounds__(256) void qh_fast(const float* __restrict__ h_t,
                                               const float* __restrict__ W_h,
                                               float* __restrict__ qh,
                                               float* __restrict__ scores) {
    __shared__ float hs[8 * 1024];
    __shared__ float red2[128][8];
    const int et = blockIdx.x;  // 0..7
    const int bg = blockIdx.y;  // 0..7
    const int t = threadIdx.x;
    const int bid = bg * 8 + et;
#pragma unroll
    for (int j = 0; j < 4; ++j) scores[bid * 1024 + j * 256 + t] = 0.f;
    const int b0 = bg * 8;
    const float4* hsrc = (const float4*)(h_t + (size_t)b0 * DD);
    float4* hdst = (float4*)hs;
    for (int i = t; i < 2048; i += 256) hdst[i] = hsrc[i];
    __syncthreads();
    const int el = t & 127;
    const int half = t >> 7;
    const int e = et * 128 + el;
    const float4* wrow = (const float4*)(W_h + (size_t)e * DD) + half * 128;
    float p[8];
#pragma unroll
    for (int bi = 0; bi < 8; ++bi) p[bi] = 0.f;
    for (int k4 = 0; k4 < 128; ++k4) {
        float4 wv = wrow[k4];
        const int kb = half * 512 + k4 * 4;
#pragma unroll
        for (int bi = 0; bi < 8; ++bi) {
            const float* hp = &hs[bi * 1024 + kb];
            p[bi] = fmaf(wv.x, hp[0], p[bi]);
            p[bi] = fmaf(wv.y, hp[1], p[bi]);
            p[bi] = fmaf(wv.z, hp[2], p[bi]);
            p[bi] = fmaf(wv.w, hp[3], p[bi]);
        }
    }
    if (half == 1) {
#pragma unroll
        for (int bi = 0; bi < 8; ++bi) red2[el][bi] = p[bi];
    }
    __syncthreads();
    if (half == 0) {
#pragma unroll
        for (int bi = 0; bi < 8; ++bi) qh[(size_t)(b0 + bi) * DD + e] = p[bi] + red2[el][bi];
    }
}

// ---- scores: fp16 MFMA GEMM, BK=64, XCD-swizzled grid, fused tanh/v epilogue ----
// grid (64, 64): bx = cp*8 + nt (same keys tile -> ids = same mod 8 -> same XCD), by = b.
__global__ __launch_bounds__(256, 4) void scores_mfma(const _Float16* __restrict__ keysT,
                                                      const _Float16* __restrict__ wkT,
                                                      const float* __restrict__ v,
                                                      const float* __restrict__ qh,
                                                      float* __restrict__ scores) {
    __shared__ _Float16 As[2 * 128 * 32];  // two 8 KB chunks
    __shared__ _Float16 Bs[2 * 128 * 32];
    __shared__ float vs[128];
    __shared__ float qs[128];
    __shared__ float red[128][2];

    const int tid = threadIdx.x;
    const int cp = blockIdx.x >> 3;  // e-tile 0..7
    const int nt = blockIdx.x & 7;   // n-tile 0..7
    const int b = blockIdx.y;
    const int e0 = cp * 128;

    if (tid < 128) {
        vs[tid] = v[e0 + tid];
        qs[tid] = qh[b * DD + e0 + tid];
    }

    const char* Abase = (const char*)(keysT + (((size_t)b * 8 + nt) * 32) * 4096);
    const char* Bbase = (const char*)(wkT + ((size_t)cp * 32) * 4096);

    const int w = tid >> 6;
    const int lane = tid & 63;
    const int wm = w & 1;
    const int we = w >> 1;
    const int lcol = lane & 15;
    const int quad = lane >> 4;
    const int soff = tid * 16;  // wave-uniform base + lane*16 within each 4 KB round

    f32x4 acc[4][4];
#pragma unroll
    for (int mi = 0; mi < 4; ++mi)
#pragma unroll
        for (int ni = 0; ni < 4; ++ni) acc[mi][ni] = (f32x4){0.f, 0.f, 0.f, 0.f};

    for (int kt2 = 0; kt2 < 16; ++kt2) {  // 16 big steps of BK=64 (two 8 KB chunks)
        __syncthreads();  // prior iteration's LDS reads done
        const char* ag = Abase + (size_t)kt2 * 16384 + soff;
        const char* bg = Bbase + (size_t)kt2 * 16384 + soff;
        char* al_ = (char*)As + soff;
        char* bl_ = (char*)Bs + soff;
#pragma unroll
        for (int r = 0; r < 4; ++r) GLOAD_LDS16(ag + r * 4096, al_ + r * 4096);
#pragma unroll
        for (int r = 0; r < 4; ++r) GLOAD_LDS16(bg + r * 4096, bl_ + r * 4096);
        __syncthreads();  // staging complete

#pragma unroll
        for (int c = 0; c < 2; ++c) {
            f16x8 af[4], bf[4];
#pragma unroll
            for (int mi = 0; mi < 4; ++mi)
                af[mi] = *(const f16x8*)&As[c * 4096 + (wm * 64 + mi * 16 + lcol) * 32 + quad * 8];
#pragma unroll
            for (int ni = 0; ni < 4; ++ni)
                bf[ni] = *(const f16x8*)&Bs[c * 4096 + (we * 64 + ni * 16 + lcol) * 32 + quad * 8];
#pragma unroll
            for (int mi = 0; mi < 4; ++mi)
#pragma unroll
                for (int ni = 0; ni < 4; ++ni)
                    acc[mi][ni] = __builtin_amdgcn_mfma_f32_16x16x32_f16(af[mi], bf[ni], acc[mi][ni], 0, 0, 0);
        }
    }

    // epilogue: partial score = sum_e v[e]*tanh(qh[e]+acc); C/D: col=lane&15 (e), row=quad*4+reg (n)
    float part[4][4];
#pragma unroll
    for (int mi = 0; mi < 4; ++mi)
#pragma unroll
        for (int r = 0; r < 4; ++r) part[mi][r] = 0.f;
#pragma unroll
    for (int mi = 0; mi < 4; ++mi)
#pragma unroll
        for (int ni = 0; ni < 4; ++ni) {
            const int e = we * 64 + ni * 16 + lcol;
            const float vv = vs[e];
            const float qv = qs[e];
#pragma unroll
            for (int r = 0; r < 4; ++r)
                part[mi][r] += vv * fast_tanh(qv + acc[mi][ni][r]);
        }
#pragma unroll
    for (int mi = 0; mi < 4; ++mi)
#pragma unroll
        for (int r = 0; r < 4; ++r) {
            float p = part[mi][r];
            p += __shfl_xor(p, 1);
            p += __shfl_xor(p, 2);
            p += __shfl_xor(p, 4);
            p += __shfl_xor(p, 8);
            if (lcol == 0) red[wm * 64 + mi * 16 + quad * 4 + r][we] = p;
        }
    __syncthreads();
    if (tid < 128) atomicAdd(&scores[b * NN + nt * 128 + tid], red[tid][0] + red[tid][1]);
}

// ---- softmax; zeroes context ----
__global__ __launch_bounds__(256) void softmax_kernel(const float* __restrict__ scores,
                                                      float* __restrict__ alpha,
                                                      float* __restrict__ context) {
    const int b = blockIdx.x;
    const int t = threadIdx.x;
#pragma unroll
    for (int j = 0; j < 4; ++j) context[b * DD + t + 256 * j] = 0.f;
    float x[4];
    float m = -1e30f;
#pragma unroll
    for (int j = 0; j < 4; ++j) {
        x[j] = scores[b * NN + t + 256 * j];
        m = fmaxf(m, x[j]);
    }
#pragma unroll
    for (int mask = 32; mask >= 1; mask >>= 1) m = fmaxf(m, __shfl_xor(m, mask));
    __shared__ float wred[4];
    __shared__ float wsum[4];
    const int wv = t >> 6;
    if ((t & 63) == 0) wred[wv] = m;
    __syncthreads();
    m = fmaxf(fmaxf(wred[0], wred[1]), fmaxf(wred[2], wred[3]));
    float s = 0.f;
#pragma unroll
    for (int j = 0; j < 4; ++j) {
        x[j] = expf(x[j] - m);
        s += x[j];
    }
#pragma unroll
    for (int mask = 32; mask >= 1; mask >>= 1) s += __shfl_xor(s, mask);
    if ((t & 63) == 0) wsum[wv] = s;
    __syncthreads();
    s = wsum[0] + wsum[1] + wsum[2] + wsum[3];
    const float inv = 1.f / s;
#pragma unroll
    for (int j = 0; j < 4; ++j) alpha[b * NN + t + 256 * j] = x[j] * inv;
}

// ---- context from fp32 keys, coalesced float4; grid (16, 64), 64-row chunks ----
__global__ __launch_bounds__(256) void context_f32(const float* __restrict__ keys,
                                                   const float* __restrict__ alpha,
                                                   float* __restrict__ context) {
    const int b = blockIdx.y;
    const int nc = blockIdx.x;  // 0..15
    const int t = threadIdx.x;
    __shared__ float al[64];
    if (t < 64) al[t] = alpha[b * NN + nc * 64 + t];
    __syncthreads();
    const float4* kp = (const float4*)(keys + ((size_t)b * NN + nc * 64) * DD);
    float4 acc = {0.f, 0.f, 0.f, 0.f};
#pragma unroll 4
    for (int n = 0; n < 64; ++n) {
        const float a = al[n];
        float4 kv = kp[(size_t)n * (DD / 4) + t];
        acc.x = fmaf(a, kv.x, acc.x);
        acc.y = fmaf(a, kv.y, acc.y);
        acc.z = fmaf(a, kv.z, acc.z);
        acc.w = fmaf(a, kv.w, acc.w);
    }
    float* cp = context + b * DD + 4 * t;
    atomicAdd(cp + 0, acc.x);
    atomicAdd(cp + 1, acc.y);
    atomicAdd(cp + 2, acc.z);
    atomicAdd(cp + 3, acc.w);
}

// =========================== FALLBACK PATH (round-2, used if ws too small) ===========================
__global__ __launch_bounds__(256) void qh_fb(const float* __restrict__ h_t,
                                             const float* __restrict__ W_h,
                                             float* __restrict__ qh,
                                             float* __restrict__ scores) {
    __shared__ float hs[DD];
    const int b = blockIdx.y;
    const int e = blockIdx.x * 256 + threadIdx.x;
    scores[(blockIdx.y * 4 + blockIdx.x) * 256 + threadIdx.x] = 0.f;
    for (int i = threadIdx.x; i < DD; i += 256) hs[i] = h_t[b * DD + i];
    __syncthreads();
    const float4* wrow = (const float4*)(W_h + (size_t)e * DD);
    float acc = 0.f;
#pragma unroll 4
    for (int k4 = 0; k4 < DD / 4; ++k4) {
        float4 w = wrow[k4];
        acc = fmaf(w.x, hs[4 * k4 + 0], acc);
        acc = fmaf(w.y, hs[4 * k4 + 1], acc);
        acc = fmaf(w.z, hs[4 * k4 + 2], acc);
        acc = fmaf(w.w, hs[4 * k4 + 3], acc);
    }
    qh[b * DD + e] = acc;
}

#define SPAD 40
__device__ __forceinline__ void split16(const float4* __restrict__ src,
                                        unsigned short* hi, unsigned short* lo) {
    float x[16];
    float4 v0 = src[0], v1 = src[1], v2 = src[2], v3 = src[3];
    x[0] = v0.x; x[1] = v0.y; x[2] = v0.z; x[3] = v0.w;
    x[4] = v1.x; x[5] = v1.y; x[6] = v1.z; x[7] = v1.w;
    x[8] = v2.x; x[9] = v2.y; x[10] = v2.z; x[11] = v2.w;
    x[12] = v3.x; x[13] = v3.y; x[14] = v3.z; x[15] = v3.w;
#pragma unroll
    for (int i = 0; i < 16; ++i) {
        unsigned int u = __float_as_uint(x[i]);
        hi[i] = (unsigned short)(u >> 16);
        float hif = __uint_as_float(u & 0xFFFF0000u);
        float lof = x[i] - hif;
        lo[i] = (unsigned short)(__float_as_uint(lof) >> 16);
    }
}

__global__ __launch_bounds__(256, 2) void scores_fb(const float* __restrict__ keys,
                                                    const float* __restrict__ W_k,
                                                    const float* __restrict__ v,
                                                    const float* __restrict__ qh,
                                                    float* __restrict__ scores) {
    __shared__ unsigned short Ah[128 * SPAD];
    __shared__ unsigned short Al[128 * SPAD];
    __shared__ unsigned short Bh[128 * SPAD];
    __shared__ unsigned short Bl[128 * SPAD];
    __shared__ float vs[128];
    __shared__ float qs[128];
    __shared__ float red[128][2];

    const int tid = threadIdx.x;
    const int cp = blockIdx.x;
    const int rt = blockIdx.y;
    const int b = rt >> 3;
    const int n0 = (rt & 7) * 128;
    const int e0 = cp * 128;
    if (tid < 128) {
        vs[tid] = v[e0 + tid];
        qs[tid] = qh[b * DD + e0 + tid];
    }
    const float* Ag = keys + ((size_t)b * NN + n0) * DD;
    const float* Bg = W_k + (size_t)e0 * DD;
    const int w = tid >> 6;
    const int lane = tid & 63;
    const int wm = w & 1;
    const int we = w >> 1;
    const int lcol = lane & 15;
    const int quad = lane >> 4;
    f32x4 acc[4][4];
#pragma unroll
    for (int mi = 0; mi < 4; ++mi)
#pragma unroll
        for (int ni = 0; ni < 4; ++ni) acc[mi][ni] = (f32x4){0.f, 0.f, 0.f, 0.f};
    const int srow = tid >> 1;
    const int sseg = tid & 1;
    float4 pa[4], pb[4];
    {
        const float4* as = (const float4*)(Ag + (size_t)srow * DD + sseg * 16);
        const float4* bs = (const float4*)(Bg + (size_t)srow * DD + sseg * 16);
#pragma unroll
        for (int i = 0; i < 4; ++i) { pa[i] = as[i]; pb[i] = bs[i]; }
    }
    for (int kt = 0; kt < DD / 32; ++kt) {
        __syncthreads();
        {
            unsigned short hi[16], lo[16];
            split16(pa, hi, lo);
            u16x8* dh = (u16x8*)&Ah[srow * SPAD + sseg * 16];
            u16x8* dl = (u16x8*)&Al[srow * SPAD + sseg * 16];
            dh[0] = *(u16x8*)&hi[0]; dh[1] = *(u16x8*)&hi[8];
            dl[0] = *(u16x8*)&lo[0]; dl[1] = *(u16x8*)&lo[8];
            split16(pb, hi, lo);
            u16x8* eh = (u16x8*)&Bh[srow * SPAD + sseg * 16];
            u16x8* el = (u16x8*)&Bl[srow * SPAD + sseg * 16];
            eh[0] = *(u16x8*)&hi[0]; eh[1] = *(u16x8*)&hi[8];
            el[0] = *(u16x8*)&lo[0]; el[1] = *(u16x8*)&lo[8];
        }
        if (kt + 1 < DD / 32) {
            const int k0 = (kt + 1) * 32;
            const float4* as = (const float4*)(Ag + (size_t)srow * DD + k0 + sseg * 16);
            const float4* bs = (const float4*)(Bg + (size_t)srow * DD + k0 + sseg * 16);
#pragma unroll
            for (int i = 0; i < 4; ++i) { pa[i] = as[i]; pb[i] = bs[i]; }
        }
        __syncthreads();
        bf16x8 ah[4], al2[4], bh[4], bl2[4];
#pragma unroll
        for (int mi = 0; mi < 4; ++mi) {
            const int r = wm * 64 + mi * 16 + lcol;
            ah[mi] = *(const bf16x8*)&Ah[r * SPAD + quad * 8];
            al2[mi] = *(const bf16x8*)&Al[r * SPAD + quad * 8];
        }
#pragma unroll
        for (int ni = 0; ni < 4; ++ni) {
            const int r = we * 64 + ni * 16 + lcol;
            bh[ni] = *(const bf16x8*)&Bh[r * SPAD + quad * 8];
            bl2[ni] = *(const bf16x8*)&Bl[r * SPAD + quad * 8];
        }
#pragma unroll
        for (int mi = 0; mi < 4; ++mi)
#pragma unroll
            for (int ni = 0; ni < 4; ++ni) {
                acc[mi][ni] = __builtin_amdgcn_mfma_f32_16x16x32_bf16(ah[mi], bh[ni], acc[mi][ni], 0, 0, 0);
                acc[mi][ni] = __builtin_amdgcn_mfma_f32_16x16x32_bf16(ah[mi], bl2[ni], acc[mi][ni], 0, 0, 0);
                acc[mi][ni] = __builtin_amdgcn_mfma_f32_16x16x32_bf16(al2[mi], bh[ni], acc[mi][ni], 0, 0, 0);
            }
    }
    float part[4][4];
#pragma unroll
    for (int mi = 0; mi < 4; ++mi)
#pragma unroll
        for (int r = 0; r < 4; ++r) part[mi][r] = 0.f;
#pragma unroll
    for (int mi = 0; mi < 4; ++mi)
#pragma unroll
        for (int ni = 0; ni < 4; ++ni) {
            const int e = we * 64 + ni * 16 + lcol;
            const float vv = vs[e];
            const float qv = qs[e];
#pragma unroll
            for (int r = 0; r < 4; ++r)
                part[mi][r] += vv * fast_tanh(qv + acc[mi][ni][r]);
        }
#pragma unroll
    for (int mi = 0; mi < 4; ++mi)
#pragma unroll
        for (int r = 0; r < 4; ++r) {
            float p = part[mi][r];
            p += __shfl_xor(p, 1);
            p += __shfl_xor(p, 2);
            p += __shfl_xor(p, 4);
            p += __shfl_xor(p, 8);
            if (lcol == 0) red[wm * 64 + mi * 16 + quad * 4 + r][we] = p;
        }
    __syncthreads();
    if (tid < 128) atomicAdd(&scores[b * NN + n0 + tid], red[tid][0] + red[tid][1]);
}

extern "C" void kernel_launch(void* const* d_in, const int* in_sizes, int n_in,
                              void* d_out, int out_size, void* d_ws, size_t ws_size,
                              hipStream_t stream) {
    const float* h_t = (const float*)d_in[0];
    const float* keys = (const float*)d_in[1];
    const float* W_h = (const float*)d_in[2];
    const float* W_k = (const float*)d_in[3];
    const float* v = (const float*)d_in[4];

    float* context = (float*)d_out;          // [B, D]
    float* alpha = (float*)d_out + BB * DD;  // [B, N]
    float* qh = (float*)d_ws;                // [B, D]
    float* scores = (float*)d_ws + BB * DD;  // [B, N]

    const size_t wkT_off = (size_t)2 * BB * DD * sizeof(float);  // 512 KB
    const size_t keysT_off = wkT_off + (size_t)DD * DD * 2;      // +2 MB
    const size_t need = keysT_off + (size_t)BB * NN * DD * 2;    // +128 MB

    if (ws_size >= need) {
        _Float16* wkT = (_Float16*)((char*)d_ws + wkT_off);
        _Float16* keysT = (_Float16*)((char*)d_ws + keysT_off);
        cvt_all<<<dim3(8, 65), 256, 0, stream>>>(keys, W_k, keysT, wkT);
        qh_fast<<<dim3(8, 8), 256, 0, stream>>>(h_t, W_h, qh, scores);
        scores_mfma<<<dim3(64, 64), 256, 0, stream>>>(keysT, wkT, v, qh, scores);
        softmax_kernel<<<BB, 256, 0, stream>>>(scores, alpha, context);
        context_f32<<<dim3(16, BB), 256, 0, stream>>>(keys, alpha, context);
    } else {
        qh_fb<<<dim3(4, BB), 256, 0, stream>>>(h_t, W_h, qh, scores);
        scores_fb<<<dim3(8, 512), 256, 0, stream>>>(keys, W_k, v, qh, scores);
        softmax_kernel<<<BB, 256, 0, stream>>>(scores, alpha, context);
        context_f32<<<dim3(16, BB), 256, 0, stream>>>(keys, alpha, context);
    }
}

// Round 5
// 622.980 us; speedup vs baseline: 3.3484x; 1.0380x over previous
//
#include <hip/hip_runtime.h>
#include <math.h>

#define BB 64
#define NN 1024
#define DD 1024

typedef __bf16 bf16x8 __attribute__((ext_vector_type(8)));
typedef _Float16 f16x8 __attribute__((ext_vector_type(8)));
typedef float f32x4 __attribute__((ext_vector_type(4)));
typedef unsigned short u16x8 __attribute__((ext_vector_type(8)));

#define GLOAD_LDS16(g, l)                                                  \
    __builtin_amdgcn_global_load_lds(                                      \
        (const __attribute__((address_space(1))) unsigned int*)(g),        \
        (__attribute__((address_space(3))) unsigned int*)(l), 16, 0, 0)

__device__ __forceinline__ float fast_tanh(float x) {
    return 1.f - 2.f / (__expf(2.f * x) + 1.f);
}

// ws layout:
//   qh      fp32 [BB*DD]                     @ 0
//   scores  fp32 [BB*NN]                     @ 65536 floats
//   wkT     fp16 [8 et][32 kt][128*32]       @ byte 524288   (2 MB)
//   keysT   fp16 [64 b][8 nt][32 kt][128*32] @ byte 2621440  (128 MB)

// ---- k_cvt: keys (and W_k as bb==64) fp32 -> fp16 tiled chunks ----
// grid (8 nt, 65 bb, 4 ks); each block does 8 kt chunks. Wave writes 1 KB contiguous.
__global__ __launch_bounds__(256) void k_cvt(const float* __restrict__ keys,
                                             const float* __restrict__ W_k,
                                             _Float16* __restrict__ keysT,
                                             _Float16* __restrict__ wkT) {
    const int nt = blockIdx.x;  // 8
    const int bb = blockIdx.y;  // 0..64 (64 = W_k)
    const int ks = blockIdx.z;  // 0..3
    const int t = threadIdx.x;
    const float* src = (bb == 64) ? (W_k + (size_t)nt * 128 * DD)
                                  : (keys + ((size_t)bb * NN + nt * 128) * DD);
    _Float16* dst = (bb == 64) ? (wkT + (size_t)nt * 32 * 4096)
                               : (keysT + (((size_t)bb * 8 + nt) * 32) * 4096);
    const int p0 = t * 8;
    const int n0 = p0 >> 5;
    const int k0 = p0 & 31;
    for (int kt = ks * 8; kt < ks * 8 + 8; ++kt) {
#pragma unroll
        for (int r = 0; r < 2; ++r) {
            const int n = n0 + r * 64;
            const float4* s4 = (const float4*)(src + (size_t)n * DD + kt * 32 + k0);
            float4 a = s4[0], b4 = s4[1];
            f16x8 h = {(_Float16)a.x,  (_Float16)a.y,  (_Float16)a.z,  (_Float16)a.w,
                       (_Float16)b4.x, (_Float16)b4.y, (_Float16)b4.z, (_Float16)b4.w};
            *(f16x8*)(dst + (size_t)kt * 4096 + r * 2048 + p0) = h;
        }
    }
}

// ---- k_qh: qh[b, et*128..+128] = h_t[b] @ W_h.T slice; zeroes scores slice ----
// grid (64 b, 8 et): b fastest -> all XCDs stream the same W_h slice (L2/L3-served).
__global__ __launch_bounds__(256) void k_qh(const float* __restrict__ h_t,
                                            const float* __restrict__ W_h,
                                            float* __restrict__ qh,
                                            float* __restrict__ scores) {
    __shared__ float hs[DD];
    __shared__ float red2[128];
    const int b = blockIdx.x;   // 0..63
    const int et = blockIdx.y;  // 0..7
    const int t = threadIdx.x;
    if (t < 128) scores[b * NN + et * 128 + t] = 0.f;
    ((float4*)hs)[t] = ((const float4*)(h_t + (size_t)b * DD))[t];
    __syncthreads();
    const int el = t & 127;
    const int half = t >> 7;
    const int e = et * 128 + el;
    const float4* wrow = (const float4*)(W_h + (size_t)e * DD) + half * 128;
    const float* hp = hs + half * 512;
    float acc = 0.f;
#pragma unroll 4
    for (int k4 = 0; k4 < 128; ++k4) {
        float4 wv = wrow[k4];
        acc = fmaf(wv.x, hp[4 * k4 + 0], acc);
        acc = fmaf(wv.y, hp[4 * k4 + 1], acc);
        acc = fmaf(wv.z, hp[4 * k4 + 2], acc);
        acc = fmaf(wv.w, hp[4 * k4 + 3], acc);
    }
    if (half == 1) red2[el] = acc;
    __syncthreads();
    if (half == 0) qh[(size_t)b * DD + e] = acc + red2[el];
}

// ---- k_sc: fp16 MFMA GEMM, BK=64, XCD-swizzled grid, fused tanh/v epilogue ----
// grid (64, 64): bx = cp*8 + nt (keys tile shared by ids = same mod 8 -> same XCD), by = b.
__global__ __launch_bounds__(256, 4) void k_sc(const _Float16* __restrict__ keysT,
                                               const _Float16* __restrict__ wkT,
                                               const float* __restrict__ v,
                                               const float* __restrict__ qh,
                                               float* __restrict__ scores) {
    __shared__ _Float16 As[2 * 128 * 32];  // 16 KB
    __shared__ _Float16 Bs[2 * 128 * 32];
    __shared__ float vs[128];
    __shared__ float qs[128];
    __shared__ float red[128][2];

    const int tid = threadIdx.x;
    const int cp = blockIdx.x >> 3;  // e-tile 0..7
    const int nt = blockIdx.x & 7;   // n-tile 0..7
    const int b = blockIdx.y;
    const int e0 = cp * 128;

    if (tid < 128) {
        vs[tid] = v[e0 + tid];
        qs[tid] = qh[b * DD + e0 + tid];
    }

    const char* Abase = (const char*)(keysT + (((size_t)b * 8 + nt) * 32) * 4096);
    const char* Bbase = (const char*)(wkT + ((size_t)cp * 32) * 4096);

    const int w = tid >> 6;
    const int lane = tid & 63;
    const int wm = w & 1;
    const int we = w >> 1;
    const int lcol = lane & 15;
    const int quad = lane >> 4;
    const int soff = tid * 16;

    f32x4 acc[4][4];
#pragma unroll
    for (int mi = 0; mi < 4; ++mi)
#pragma unroll
        for (int ni = 0; ni < 4; ++ni) acc[mi][ni] = (f32x4){0.f, 0.f, 0.f, 0.f};

    for (int kt2 = 0; kt2 < 16; ++kt2) {  // BK=64: two 8 KB chunks per side
        __syncthreads();
        const char* ag = Abase + (size_t)kt2 * 16384 + soff;
        const char* bg = Bbase + (size_t)kt2 * 16384 + soff;
        char* al_ = (char*)As + soff;
        char* bl_ = (char*)Bs + soff;
#pragma unroll
        for (int r = 0; r < 4; ++r) GLOAD_LDS16(ag + r * 4096, al_ + r * 4096);
#pragma unroll
        for (int r = 0; r < 4; ++r) GLOAD_LDS16(bg + r * 4096, bl_ + r * 4096);
        __syncthreads();

#pragma unroll
        for (int c = 0; c < 2; ++c) {
            f16x8 af[4], bf[4];
#pragma unroll
            for (int mi = 0; mi < 4; ++mi)
                af[mi] = *(const f16x8*)&As[c * 4096 + (wm * 64 + mi * 16 + lcol) * 32 + quad * 8];
#pragma unroll
            for (int ni = 0; ni < 4; ++ni)
                bf[ni] = *(const f16x8*)&Bs[c * 4096 + (we * 64 + ni * 16 + lcol) * 32 + quad * 8];
#pragma unroll
            for (int mi = 0; mi < 4; ++mi)
#pragma unroll
                for (int ni = 0; ni < 4; ++ni)
                    acc[mi][ni] = __builtin_amdgcn_mfma_f32_16x16x32_f16(af[mi], bf[ni], acc[mi][ni], 0, 0, 0);
        }
    }

    // epilogue: C/D layout col=lane&15 (e), row=quad*4+reg (n)
    float part[4][4];
#pragma unroll
    for (int mi = 0; mi < 4; ++mi)
#pragma unroll
        for (int r = 0; r < 4; ++r) part[mi][r] = 0.f;
#pragma unroll
    for (int mi = 0; mi < 4; ++mi)
#pragma unroll
        for (int ni = 0; ni < 4; ++ni) {
            const int e = we * 64 + ni * 16 + lcol;
            const float vv = vs[e];
            const float qv = qs[e];
#pragma unroll
            for (int r = 0; r < 4; ++r)
                part[mi][r] += vv * fast_tanh(qv + acc[mi][ni][r]);
        }
#pragma unroll
    for (int mi = 0; mi < 4; ++mi)
#pragma unroll
        for (int r = 0; r < 4; ++r) {
            float p = part[mi][r];
            p += __shfl_xor(p, 1);
            p += __shfl_xor(p, 2);
            p += __shfl_xor(p, 4);
            p += __shfl_xor(p, 8);
            if (lcol == 0) red[wm * 64 + mi * 16 + quad * 4 + r][we] = p;
        }
    __syncthreads();
    if (tid < 128) atomicAdd(&scores[b * NN + nt * 128 + tid], red[tid][0] + red[tid][1]);
}

// ---- k_sm: softmax; zeroes nothing (context written directly by k_ctx) ----
__global__ __launch_bounds__(256) void k_sm(const float* __restrict__ scores,
                                            float* __restrict__ alpha) {
    const int b = blockIdx.x;
    const int t = threadIdx.x;
    float x[4];
    float m = -1e30f;
#pragma unroll
    for (int j = 0; j < 4; ++j) {
        x[j] = scores[b * NN + t + 256 * j];
        m = fmaxf(m, x[j]);
    }
#pragma unroll
    for (int mask = 32; mask >= 1; mask >>= 1) m = fmaxf(m, __shfl_xor(m, mask));
    __shared__ float wred[4];
    __shared__ float wsum[4];
    const int wv = t >> 6;
    if ((t & 63) == 0) wred[wv] = m;
    __syncthreads();
    m = fmaxf(fmaxf(wred[0], wred[1]), fmaxf(wred[2], wred[3]));
    float s = 0.f;
#pragma unroll
    for (int j = 0; j < 4; ++j) {
        x[j] = expf(x[j] - m);
        s += x[j];
    }
#pragma unroll
    for (int mask = 32; mask >= 1; mask >>= 1) s += __shfl_xor(s, mask);
    if ((t & 63) == 0) wsum[wv] = s;
    __syncthreads();
    s = wsum[0] + wsum[1] + wsum[2] + wsum[3];
    const float inv = 1.f / s;
#pragma unroll
    for (int j = 0; j < 4; ++j) alpha[b * NN + t + 256 * j] = x[j] * inv;
}

// ---- k_ctx: context[b, kt*32..+32] = sum_n alpha[b,n]*keysT chunks; no atomics ----
// grid (32 kt, 64 b). Coalesced 8 KB chunk reads; LDS tree reduce; exclusive d-range.
__global__ __launch_bounds__(256) void k_ctx(const _Float16* __restrict__ keysT,
                                             const float* __restrict__ alpha,
                                             float* __restrict__ context) {
    __shared__ float al[NN];
    __shared__ float red[64][33];
    const int kt = blockIdx.x;  // 0..31
    const int b = blockIdx.y;   // 0..63
    const int t = threadIdx.x;
#pragma unroll
    for (int j = 0; j < 4; ++j) al[t + 256 * j] = alpha[b * NN + t + 256 * j];
    __syncthreads();

    const int p0 = t * 8;
    const int g = t >> 2;         // 0..63: n within half-chunk
    const int q = t & 3;          // k-octet
    float acc[8];
#pragma unroll
    for (int j = 0; j < 8; ++j) acc[j] = 0.f;

    for (int nt = 0; nt < 8; ++nt) {
        const _Float16* base = keysT + (((size_t)b * 8 + nt) * 32 + kt) * 4096;
#pragma unroll
        for (int r = 0; r < 2; ++r) {
            f16x8 kv = *(const f16x8*)(base + r * 2048 + p0);
            const float a = al[nt * 128 + r * 64 + g];
#pragma unroll
            for (int j = 0; j < 8; ++j) acc[j] = fmaf(a, (float)kv[j], acc[j]);
        }
    }
#pragma unroll
    for (int j = 0; j < 8; ++j) red[g][q * 8 + j] = acc[j];
    __syncthreads();
    if (t < 32) {
        float s = 0.f;
#pragma unroll 8
        for (int n = 0; n < 64; ++n) s += red[n][t];
        context[(size_t)b * DD + kt * 32 + t] = s;
    }
}

// =========================== FALLBACK PATH (used if ws too small) ===========================
__global__ __launch_bounds__(256) void qh_fb(const float* __restrict__ h_t,
                                             const float* __restrict__ W_h,
                                             float* __restrict__ qh,
                                             float* __restrict__ scores) {
    __shared__ float hs[DD];
    const int b = blockIdx.y;
    const int e = blockIdx.x * 256 + threadIdx.x;
    scores[(blockIdx.y * 4 + blockIdx.x) * 256 + threadIdx.x] = 0.f;
    for (int i = threadIdx.x; i < DD; i += 256) hs[i] = h_t[b * DD + i];
    __syncthreads();
    const float4* wrow = (const float4*)(W_h + (size_t)e * DD);
    float acc = 0.f;
#pragma unroll 4
    for (int k4 = 0; k4 < DD / 4; ++k4) {
        float4 w = wrow[k4];
        acc = fmaf(w.x, hs[4 * k4 + 0], acc);
        acc = fmaf(w.y, hs[4 * k4 + 1], acc);
        acc = fmaf(w.z, hs[4 * k4 + 2], acc);
        acc = fmaf(w.w, hs[4 * k4 + 3], acc);
    }
    qh[b * DD + e] = acc;
}

#define SPAD 40
__device__ __forceinline__ void split16(const float4* __restrict__ src,
                                        unsigned short* hi, unsigned short* lo) {
    float x[16];
    float4 v0 = src[0], v1 = src[1], v2 = src[2], v3 = src[3];
    x[0] = v0.x; x[1] = v0.y; x[2] = v0.z; x[3] = v0.w;
    x[4] = v1.x; x[5] = v1.y; x[6] = v1.z; x[7] = v1.w;
    x[8] = v2.x; x[9] = v2.y; x[10] = v2.z; x[11] = v2.w;
    x[12] = v3.x; x[13] = v3.y; x[14] = v3.z; x[15] = v3.w;
#pragma unroll
    for (int i = 0; i < 16; ++i) {
        unsigned int u = __float_as_uint(x[i]);
        hi[i] = (unsigned short)(u >> 16);
        float hif = __uint_as_float(u & 0xFFFF0000u);
        float lof = x[i] - hif;
        lo[i] = (unsigned short)(__float_as_uint(lof) >> 16);
    }
}

__global__ __launch_bounds__(256, 2) void scores_fb(const float* __restrict__ keys,
                                                    const float* __restrict__ W_k,
                                                    const float* __restrict__ v,
                                                    const float* __restrict__ qh,
                                                    float* __restrict__ scores) {
    __shared__ unsigned short Ah[128 * SPAD];
    __shared__ unsigned short Al[128 * SPAD];
    __shared__ unsigned short Bh[128 * SPAD];
    __shared__ unsigned short Bl[128 * SPAD];
    __shared__ float vs[128];
    __shared__ float qs[128];
    __shared__ float red[128][2];

    const int tid = threadIdx.x;
    const int cp = blockIdx.x;
    const int rt = blockIdx.y;
    const int b = rt >> 3;
    const int n0 = (rt & 7) * 128;
    const int e0 = cp * 128;
    if (tid < 128) {
        vs[tid] = v[e0 + tid];
        qs[tid] = qh[b * DD + e0 + tid];
    }
    const float* Ag = keys + ((size_t)b * NN + n0) * DD;
    const float* Bg = W_k + (size_t)e0 * DD;
    const int w = tid >> 6;
    const int lane = tid & 63;
    const int wm = w & 1;
    const int we = w >> 1;
    const int lcol = lane & 15;
    const int quad = lane >> 4;
    f32x4 acc[4][4];
#pragma unroll
    for (int mi = 0; mi < 4; ++mi)
#pragma unroll
        for (int ni = 0; ni < 4; ++ni) acc[mi][ni] = (f32x4){0.f, 0.f, 0.f, 0.f};
    const int srow = tid >> 1;
    const int sseg = tid & 1;
    float4 pa[4], pb[4];
    {
        const float4* as = (const float4*)(Ag + (size_t)srow * DD + sseg * 16);
        const float4* bs = (const float4*)(Bg + (size_t)srow * DD + sseg * 16);
#pragma unroll
        for (int i = 0; i < 4; ++i) { pa[i] = as[i]; pb[i] = bs[i]; }
    }
    for (int kt = 0; kt < DD / 32; ++kt) {
        __syncthreads();
        {
            unsigned short hi[16], lo[16];
            split16(pa, hi, lo);
            u16x8* dh = (u16x8*)&Ah[srow * SPAD + sseg * 16];
            u16x8* dl = (u16x8*)&Al[srow * SPAD + sseg * 16];
            dh[0] = *(u16x8*)&hi[0]; dh[1] = *(u16x8*)&hi[8];
            dl[0] = *(u16x8*)&lo[0]; dl[1] = *(u16x8*)&lo[8];
            split16(pb, hi, lo);
            u16x8* eh = (u16x8*)&Bh[srow * SPAD + sseg * 16];
            u16x8* el = (u16x8*)&Bl[srow * SPAD + sseg * 16];
            eh[0] = *(u16x8*)&hi[0]; eh[1] = *(u16x8*)&hi[8];
            el[0] = *(u16x8*)&lo[0]; el[1] = *(u16x8*)&lo[8];
        }
        if (kt + 1 < DD / 32) {
            const int k0 = (kt + 1) * 32;
            const float4* as = (const float4*)(Ag + (size_t)srow * DD + k0 + sseg * 16);
            const float4* bs = (const float4*)(Bg + (size_t)srow * DD + k0 + sseg * 16);
#pragma unroll
            for (int i = 0; i < 4; ++i) { pa[i] = as[i]; pb[i] = bs[i]; }
        }
        __syncthreads();
        bf16x8 ah[4], al2[4], bh[4], bl2[4];
#pragma unroll
        for (int mi = 0; mi < 4; ++mi) {
            const int r = wm * 64 + mi * 16 + lcol;
            ah[mi] = *(const bf16x8*)&Ah[r * SPAD + quad * 8];
            al2[mi] = *(const bf16x8*)&Al[r * SPAD + quad * 8];
        }
#pragma unroll
        for (int ni = 0; ni < 4; ++ni) {
            const int r = we * 64 + ni * 16 + lcol;
            bh[ni] = *(const bf16x8*)&Bh[r * SPAD + quad * 8];
            bl2[ni] = *(const bf16x8*)&Bl[r * SPAD + quad * 8];
        }
#pragma unroll
        for (int mi = 0; mi < 4; ++mi)
#pragma unroll
            for (int ni = 0; ni < 4; ++ni) {
                acc[mi][ni] = __builtin_amdgcn_mfma_f32_16x16x32_bf16(ah[mi], bh[ni], acc[mi][ni], 0, 0, 0);
                acc[mi][ni] = __builtin_amdgcn_mfma_f32_16x16x32_bf16(ah[mi], bl2[ni], acc[mi][ni], 0, 0, 0);
                acc[mi][ni] = __builtin_amdgcn_mfma_f32_16x16x32_bf16(al2[mi], bh[ni], acc[mi][ni], 0, 0, 0);
            }
    }
    float part[4][4];
#pragma unroll
    for (int mi = 0; mi < 4; ++mi)
#pragma unroll
        for (int r = 0; r < 4; ++r) part[mi][r] = 0.f;
#pragma unroll
    for (int mi = 0; mi < 4; ++mi)
#pragma unroll
        for (int ni = 0; ni < 4; ++ni) {
            const int e = we * 64 + ni * 16 + lcol;
            const float vv = vs[e];
            const float qv = qs[e];
#pragma unroll
            for (int r = 0; r < 4; ++r)
                part[mi][r] += vv * fast_tanh(qv + acc[mi][ni][r]);
        }
#pragma unroll
    for (int mi = 0; mi < 4; ++mi)
#pragma unroll
        for (int r = 0; r < 4; ++r) {
            float p = part[mi][r];
            p += __shfl_xor(p, 1);
            p += __shfl_xor(p, 2);
            p += __shfl_xor(p, 4);
            p += __shfl_xor(p, 8);
            if (lcol == 0) red[wm * 64 + mi * 16 + quad * 4 + r][we] = p;
        }
    __syncthreads();
    if (tid < 128) atomicAdd(&scores[b * NN + n0 + tid], red[tid][0] + red[tid][1]);
}

__global__ __launch_bounds__(256) void sm_fb(const float* __restrict__ scores,
                                             float* __restrict__ alpha,
                                             float* __restrict__ context) {
    const int b = blockIdx.x;
    const int t = threadIdx.x;
#pragma unroll
    for (int j = 0; j < 4; ++j) context[b * DD + t + 256 * j] = 0.f;
    float x[4];
    float m = -1e30f;
#pragma unroll
    for (int j = 0; j < 4; ++j) {
        x[j] = scores[b * NN + t + 256 * j];
        m = fmaxf(m, x[j]);
    }
#pragma unroll
    for (int mask = 32; mask >= 1; mask >>= 1) m = fmaxf(m, __shfl_xor(m, mask));
    __shared__ float wred[4];
    __shared__ float wsum[4];
    const int wv = t >> 6;
    if ((t & 63) == 0) wred[wv] = m;
    __syncthreads();
    m = fmaxf(fmaxf(wred[0], wred[1]), fmaxf(wred[2], wred[3]));
    float s = 0.f;
#pragma unroll
    for (int j = 0; j < 4; ++j) {
        x[j] = expf(x[j] - m);
        s += x[j];
    }
#pragma unroll
    for (int mask = 32; mask >= 1; mask >>= 1) s += __shfl_xor(s, mask);
    if ((t & 63) == 0) wsum[wv] = s;
    __syncthreads();
    s = wsum[0] + wsum[1] + wsum[2] + wsum[3];
    const float inv = 1.f / s;
#pragma unroll
    for (int j = 0; j < 4; ++j) alpha[b * NN + t + 256 * j] = x[j] * inv;
}

__global__ __launch_bounds__(256) void ctx_fb(const float* __restrict__ keys,
                                              const float* __restrict__ alpha,
                                              float* __restrict__ context) {
    const int b = blockIdx.y;
    const int nc = blockIdx.x;
    const int t = threadIdx.x;
    __shared__ float al[64];
    if (t < 64) al[t] = alpha[b * NN + nc * 64 + t];
    __syncthreads();
    const float4* kp = (const float4*)(keys + ((size_t)b * NN + nc * 64) * DD);
    float4 acc = {0.f, 0.f, 0.f, 0.f};
#pragma unroll 4
    for (int n = 0; n < 64; ++n) {
        const float a = al[n];
        float4 kv = kp[(size_t)n * (DD / 4) + t];
        acc.x = fmaf(a, kv.x, acc.x);
        acc.y = fmaf(a, kv.y, acc.y);
        acc.z = fmaf(a, kv.z, acc.z);
        acc.w = fmaf(a, kv.w, acc.w);
    }
    float* cp = context + b * DD + 4 * t;
    atomicAdd(cp + 0, acc.x);
    atomicAdd(cp + 1, acc.y);
    atomicAdd(cp + 2, acc.z);
    atomicAdd(cp + 3, acc.w);
}

extern "C" void kernel_launch(void* const* d_in, const int* in_sizes, int n_in,
                              void* d_out, int out_size, void* d_ws, size_t ws_size,
                              hipStream_t stream) {
    const float* h_t = (const float*)d_in[0];
    const float* keys = (const float*)d_in[1];
    const float* W_h = (const float*)d_in[2];
    const float* W_k = (const float*)d_in[3];
    const float* v = (const float*)d_in[4];

    float* context = (float*)d_out;          // [B, D]
    float* alpha = (float*)d_out + BB * DD;  // [B, N]
    float* qh = (float*)d_ws;                // [B, D]
    float* scores = (float*)d_ws + BB * DD;  // [B, N]

    const size_t wkT_off = (size_t)2 * BB * DD * sizeof(float);  // 512 KB
    const size_t keysT_off = wkT_off + (size_t)DD * DD * 2;      // +2 MB
    const size_t need = keysT_off + (size_t)BB * NN * DD * 2;    // +128 MB

    if (ws_size >= need) {
        _Float16* wkT = (_Float16*)((char*)d_ws + wkT_off);
        _Float16* keysT = (_Float16*)((char*)d_ws + keysT_off);
        k_cvt<<<dim3(8, 65, 4), 256, 0, stream>>>(keys, W_k, keysT, wkT);
        k_qh<<<dim3(64, 8), 256, 0, stream>>>(h_t, W_h, qh, scores);
        k_sc<<<dim3(64, 64), 256, 0, stream>>>(keysT, wkT, v, qh, scores);
        k_sm<<<BB, 256, 0, stream>>>(scores, alpha);
        k_ctx<<<dim3(32, 64), 256, 0, stream>>>(keysT, alpha, context);
    } else {
        qh_fb<<<dim3(4, BB), 256, 0, stream>>>(h_t, W_h, qh, scores);
        scores_fb<<<dim3(8, 512), 256, 0, stream>>>(keys, W_k, v, qh, scores);
        sm_fb<<<BB, 256, 0, stream>>>(scores, alpha, context);
        ctx_fb<<<dim3(16, BB), 256, 0, stream>>>(keys, alpha, context);
    }
}